// Round 8
// baseline (183.708 us; speedup 1.0000x reference)
//
#include <hip/hip_runtime.h>

// Problem: B=8, C=512, H*W=1024 spatial, 8 heads x d=64, GROUPS=32.
// Pipeline: prep(GN+weights) -> QKV GEMM -> V-transpose -> attn -> out-proj.
// Round 20: attn STAGING REMOVED (catalog mistake #7: K/V for one bh = 256KB,
// L2-fits; per-XCD working set 2MB < 4MB L2; bh=blk&63 keeps same-bh blocks
// on one XCD). K read direct from g_qkv, V direct from g_vt (16x64B aligned
// segments/load). Deletes all GLL16s, kt/vt LDS, double-buffering, and ALL
// barriers (pt4 is wave-private). LDS 64KB -> 16KB: occupancy 2 blocks/CU ->
// ~16 waves/CU (VGPR-bound). Simple loop (T15 unnecessary without barriers);
// keeps R16 VALU diet + ones-MFMA l. Other kernels = R19.

typedef __attribute__((ext_vector_type(8))) short bf16x8;   // 8 bf16 in 4 VGPRs
typedef __attribute__((ext_vector_type(4))) short bf16x4;   // 4 bf16 (8B)
typedef __attribute__((ext_vector_type(4))) float f32x4;

#define NB 8
#define NC 512
#define HW 1024
#define NHEAD 8
#define DHEAD 64
#define GROUPS 32
#define CPG 16          // channels per group
#define QKV_N 1536

// global -> LDS direct copy, 16B per lane; lds base must be wave-uniform.
#define GLL16(gaddr, ldsaddr)                                                  \
    __builtin_amdgcn_global_load_lds(                                          \
        (const __attribute__((address_space(1))) unsigned*)(gaddr),            \
        (__attribute__((address_space(3))) unsigned*)(ldsaddr), 16, 0, 0)

// Scratch in device globals.
__device__ alignas(64) short g_xn[(size_t)8192 * 512];      // GN out, pixel-major [bs][c]
__device__ alignas(64) short g_qkv[(size_t)8192 * 1536];    // QKV GEMM out [bs][3C]
__device__ alignas(64) short g_vt[(size_t)64 * 64 * 1024];  // V^T [b*8+h][d][s]
__device__ alignas(64) short g_attno[(size_t)8192 * 512];   // attention out [bs][c]
__device__ alignas(64) short g_wqkv[(size_t)1536 * 512];    // w_qkv as bf16 [o][c]
__device__ alignas(64) short g_wout[(size_t)512 * 512];     // w_out as bf16 [o][c]

__device__ __forceinline__ float b2f(short h) {
    union { unsigned u; float f; } v;
    v.u = ((unsigned)(unsigned short)h) << 16;
    return v.f;
}
__device__ __forceinline__ short f2b(float f) {
    union { float f; unsigned u; } v;
    v.f = f;
    unsigned r = v.u + 0x7fff + ((v.u >> 16) & 1);   // RNE
    return (short)(r >> 16);
}

// ---------------------------------------------------------------------------
// Kernel 1: prep = GroupNorm (blocks 0..255) + weight conversion (256..319).
// ---------------------------------------------------------------------------
__global__ __launch_bounds__(256) void prep_kernel(
    const float* __restrict__ x, const float* __restrict__ gamma,
    const float* __restrict__ beta, const float* __restrict__ wqkv,
    const float* __restrict__ wout) {
    int tid = threadIdx.x;
    if (blockIdx.x >= 256) {                 // ---- weight conversion part
        int wb = blockIdx.x - 256;           // 0..63
        for (int i = wb * 256 + tid; i < 1536 * 512; i += 64 * 256) {
            float v = wqkv[i];
            // Q rows: fold 1/sqrt(d) AND log2(e) so attn P = 2^S (raw v_exp).
            if (i < 512 * 512) v *= 0.18033688011112042f;
            g_wqkv[i] = f2b(v);
        }
        for (int i = wb * 256 + tid; i < 512 * 512; i += 64 * 256)
            g_wout[i] = f2b(wout[i]);
        return;
    }
    // ---- GroupNorm part
    int b = blockIdx.x >> 5, g = blockIdx.x & 31;
    __shared__ alignas(16) short tile[CPG][HW];          // 32 KB
    __shared__ float red[2][4];
    __shared__ float sg[CPG], sb[CPG];
    if (tid < CPG) {
        int cg = g * CPG + tid;
        sg[tid] = gamma[cg];
        sb[tid] = beta[cg];
    }
    const float* xb = x + (size_t)b * NC * HW + (size_t)g * CPG * HW;
    float s1 = 0.f, s2 = 0.f;
    #pragma unroll
    for (int it = 0; it < 8; it++) {
        int idx = tid + it * 256;
        f32x4 v0 = *(const f32x4*)(xb + idx * 8);
        f32x4 v1 = *(const f32x4*)(xb + idx * 8 + 4);
        bf16x8 w;
        #pragma unroll
        for (int j = 0; j < 4; j++) {
            s1 += v0[j] + v1[j]; s2 += v0[j] * v0[j] + v1[j] * v1[j];
            w[j] = f2b(v0[j]); w[j + 4] = f2b(v1[j]);
        }
        *(bf16x8*)(&((short*)tile)[idx * 8]) = w;
    }
    #pragma unroll
    for (int off = 32; off; off >>= 1) { s1 += __shfl_xor(s1, off); s2 += __shfl_xor(s2, off); }
    int wid = tid >> 6;
    if ((tid & 63) == 0) { red[0][wid] = s1; red[1][wid] = s2; }
    __syncthreads();
    float t1 = red[0][0] + red[0][1] + red[0][2] + red[0][3];
    float t2 = red[1][0] + red[1][1] + red[1][2] + red[1][3];
    float mean = t1 * (1.f / 16384.f);
    float var  = t2 * (1.f / 16384.f) - mean * mean;
    float inv  = rsqrtf(var + 1e-5f);
    #pragma unroll
    for (int p = 0; p < 4; p++) {
        int s = tid * 4 + p;
        bf16x8 pk0, pk1;
        #pragma unroll
        for (int cc = 0; cc < 8; cc++) {
            pk0[cc] = f2b((b2f(tile[cc][s])     - mean) * inv * sg[cc]     + sb[cc]);
            pk1[cc] = f2b((b2f(tile[cc + 8][s]) - mean) * inv * sg[cc + 8] + sb[cc + 8]);
        }
        size_t dst = ((size_t)(b * HW + s)) * NC + g * CPG;
        *(bf16x8*)(g_xn + dst)     = pk0;
        *(bf16x8*)(g_xn + dst + 8) = pk1;
    }
}

// ---------------------------------------------------------------------------
// Kernel 2: QKV GEMM. M=8192 N=1536 K=512. BK=64 + XOR swizzle (r18).
// ---------------------------------------------------------------------------
__global__ __launch_bounds__(256) void gemm_qkv() {
    const int K = NC;
    int tid = threadIdx.x, lane = tid & 63, wid = tid >> 6;
    int quad = lane >> 4, l15 = lane & 15;
    int row0 = blockIdx.x * 128;
    int col0 = blockIdx.y * 128;
    __shared__ alignas(16) short sa[128 * 64];   // 16 KB, granule-swizzled
    __shared__ alignas(16) short sbuf[128 * 64]; // 16 KB, granule-swizzled
    int r_lo = lane >> 3;                        // row within 8-row stripe
    int s_log = (lane & 7) ^ r_lo;               // pre-swizzled source granule
    int swz = l15 & 7;                           // fragment-read swizzle
    const short* ga = g_xn   + (size_t)(row0 + wid * 32 + r_lo) * K + s_log * 8;
    const short* gb = g_wqkv + (size_t)(col0 + wid * 32 + r_lo) * K + s_log * 8;
    int mw = (wid >> 1) * 64, nw = (wid & 1) * 64;
    f32x4 acc[4][4] = {};
    for (int k = 0; k < K; k += 64) {
        #pragma unroll
        for (int c = 0; c < 4; c++) {
            GLL16(ga + (size_t)(c * 8) * K + k, &sa[(wid * 32 + c * 8) * 64]);
            GLL16(gb + (size_t)(c * 8) * K + k, &sbuf[(wid * 32 + c * 8) * 64]);
        }
        __syncthreads();
        bf16x8 af0[4], af1[4], bf0[4], bf1[4];
        #pragma unroll
        for (int m = 0; m < 4; m++) {
            int row = mw + m * 16 + l15;
            af0[m] = *(const bf16x8*)&sa[row * 64 + ((quad ^ swz) * 8)];
            af1[m] = *(const bf16x8*)&sa[row * 64 + (((4 + quad) ^ swz) * 8)];
        }
        #pragma unroll
        for (int n = 0; n < 4; n++) {
            int row = nw + n * 16 + l15;
            bf0[n] = *(const bf16x8*)&sbuf[row * 64 + ((quad ^ swz) * 8)];
            bf1[n] = *(const bf16x8*)&sbuf[row * 64 + (((4 + quad) ^ swz) * 8)];
        }
        #pragma unroll
        for (int m = 0; m < 4; m++)
            #pragma unroll
            for (int n = 0; n < 4; n++) {
                acc[m][n] = __builtin_amdgcn_mfma_f32_16x16x32_bf16(af0[m], bf0[n], acc[m][n], 0, 0, 0);
                acc[m][n] = __builtin_amdgcn_mfma_f32_16x16x32_bf16(af1[m], bf1[n], acc[m][n], 0, 0, 0);
            }
        __syncthreads();
    }
    #pragma unroll
    for (int m = 0; m < 4; m++)
        #pragma unroll
        for (int n = 0; n < 4; n++)
            #pragma unroll
            for (int r = 0; r < 4; r++) {
                int row = row0 + mw + m * 16 + quad * 4 + r;
                int col = col0 + nw + n * 16 + l15;
                g_qkv[(size_t)row * QKV_N + col] = f2b(acc[m][n][r]);
            }
}

// ---------------------------------------------------------------------------
// Kernel 2b: V transpose. g_qkv V-part [bs][c] -> g_vt[bh][d][s].
// ---------------------------------------------------------------------------
__global__ __launch_bounds__(256) void transpose_v() {
    int bh = blockIdx.x & 63, st = blockIdx.x >> 6;     // grid 1024
    int b = bh >> 3, h = bh & 7;
    int tid = threadIdx.x;
    __shared__ alignas(16) short tile[64][72];
    int s0 = st * 64;
    #pragma unroll
    for (int cc = 0; cc < 2; cc++) {
        int idx = tid + cc * 256;
        int s = idx >> 3, dc = idx & 7;
        *(bf16x8*)&tile[s][dc * 8] =
            *(const bf16x8*)(g_qkv + ((size_t)(b * HW + s0 + s)) * QKV_N + 1024 + h * DHEAD + dc * 8);
    }
    __syncthreads();
    #pragma unroll
    for (int cc = 0; cc < 2; cc++) {
        int idx = tid + cc * 256;
        int d = idx & 63, sc = idx >> 6;                // sc wave-uniform
        bf16x8 o;
        #pragma unroll
        for (int j = 0; j < 8; j++) o[j] = tile[sc * 8 + j][d];
        *(bf16x8*)(g_vt + ((size_t)(bh * 64 + d)) * HW + s0 + sc * 8) = o;
    }
}

// ---------------------------------------------------------------------------
// Kernel 3: flash attention, 32 q-rows/wave, NO STAGING, NO BARRIERS (r20).
// Grid 512: bh = blk&63 (XCD L2 sharing of K/V), qt = blk>>6 (0..7).
// K direct from g_qkv, V direct from g_vt (L1/L2-served; 16x64B segments).
// P = 2^S; cvt_pk pack; l via ones-MFMA. LDS: pt4 16KB only (wave-private).
// ---------------------------------------------------------------------------
__global__ __launch_bounds__(256) void attn_kernel() {
    int bh = blockIdx.x & 63, qt = blockIdx.x >> 6;
    int b = bh >> 3, h = bh & 7;
    int tid = threadIdx.x, lane = tid & 63, wid = tid >> 6;
    int quad = lane >> 4, l15 = lane & 15;
    __shared__ alignas(16) short pt4[4][16][32][4]; // per-wave P, 4 KB each
    int qrow0 = qt * 128 + wid * 32;

    const short* qb0 = g_qkv + ((size_t)(b * HW + qrow0 + l15)) * QKV_N + h * DHEAD + quad * 8;
    const short* qb1 = g_qkv + ((size_t)(b * HW + qrow0 + 16 + l15)) * QKV_N + h * DHEAD + quad * 8;
    bf16x8 aq0 = *(const bf16x8*)qb0;
    bf16x8 aq1 = *(const bf16x8*)(qb0 + 32);
    bf16x8 aq2 = *(const bf16x8*)qb1;
    bf16x8 aq3 = *(const bf16x8*)(qb1 + 32);
    f32x4 acc_o[2][4] = {};
    f32x4 acc_l[2] = {};                             // l via ones-MFMA
    bf16x8 vone;
    #pragma unroll
    for (int j = 0; j < 8; j++) vone[j] = (short)0x3f80;   // bf16 1.0

    // K fragment rows: g_qkv[(b*HW + t)][512 + h*64 + g*8]; V^T rows:
    // g_vt[(bh*64 + d)][s]. Per-lane 16B; 16 rows x 64B aligned segments.
    const short* kbase = g_qkv + (size_t)(b * HW) * QKV_N + 512 + h * DHEAD;
    const short* vbase = g_vt + (size_t)(bh * 64) * HW;

    for (int it = 0; it < 16; it++) {
        int t0 = it * 64;
        // S^T(64t x 32m) = K Q^T, then P = 2^S, cvt_pk-packed into pt4.
        #pragma unroll
        for (int sub = 0; sub < 4; sub++) {
            size_t trow = (size_t)(t0 + sub * 16 + l15) * QKV_N;
            bf16x8 k0 = *(const bf16x8*)(kbase + trow + quad * 8);
            bf16x8 k1 = *(const bf16x8*)(kbase + trow + (4 + quad) * 8);
            f32x4 z0 = {}, z1 = {};
            z0 = __builtin_amdgcn_mfma_f32_16x16x32_bf16(k0, aq0, z0, 0, 0, 0);
            z0 = __builtin_amdgcn_mfma_f32_16x16x32_bf16(k1, aq1, z0, 0, 0, 0);
            z1 = __builtin_amdgcn_mfma_f32_16x16x32_bf16(k0, aq2, z1, 0, 0, 0);
            z1 = __builtin_amdgcn_mfma_f32_16x16x32_bf16(k1, aq3, z1, 0, 0, 0);
            #pragma unroll
            for (int g = 0; g < 2; g++) {
                f32x4 z = g ? z1 : z0;
                float e0, e1, e2, e3;
                asm("v_exp_f32 %0, %1" : "=v"(e0) : "v"(z[0]));
                asm("v_exp_f32 %0, %1" : "=v"(e1) : "v"(z[1]));
                asm("v_exp_f32 %0, %1" : "=v"(e2) : "v"(z[2]));
                asm("v_exp_f32 %0, %1" : "=v"(e3) : "v"(z[3]));
                union { unsigned w[2]; bf16x4 s; } pk;
                asm("v_cvt_pk_bf16_f32 %0, %1, %2" : "=v"(pk.w[0]) : "v"(e0), "v"(e1));
                asm("v_cvt_pk_bf16_f32 %0, %1, %2" : "=v"(pk.w[1]) : "v"(e2), "v"(e3));
                *(bf16x4*)&pt4[wid][sub * 4 + quad][g * 16 + l15][0] = pk.s;
            }
        }
        asm volatile("" ::: "memory");               // order pt4 writes vs reads
        // A-frags of P per group: lane m=g*16+l15, t=half*32+quad*8+j.
        bf16x8 ap[2][2];
        #pragma unroll
        for (int g = 0; g < 2; g++) {
            union { bf16x4 hh[2]; bf16x8 v; } cc;
            cc.hh[0] = *(const bf16x4*)&pt4[wid][quad * 2][g * 16 + l15][0];
            cc.hh[1] = *(const bf16x4*)&pt4[wid][quad * 2 + 1][g * 16 + l15][0];
            ap[g][0] = cc.v;
            cc.hh[0] = *(const bf16x4*)&pt4[wid][8 + quad * 2][g * 16 + l15][0];
            cc.hh[1] = *(const bf16x4*)&pt4[wid][8 + quad * 2 + 1][g * 16 + l15][0];
            ap[g][1] = cc.v;
        }
        // l += P * 1 (ones-B MFMA; D[m][*] replicated across l15 lanes).
        acc_l[0] = __builtin_amdgcn_mfma_f32_16x16x32_bf16(ap[0][0], vone, acc_l[0], 0, 0, 0);
        acc_l[0] = __builtin_amdgcn_mfma_f32_16x16x32_bf16(ap[0][1], vone, acc_l[0], 0, 0, 0);
        acc_l[1] = __builtin_amdgcn_mfma_f32_16x16x32_bf16(ap[1][0], vone, acc_l[1], 0, 0, 0);
        acc_l[1] = __builtin_amdgcn_mfma_f32_16x16x32_bf16(ap[1][1], vone, acc_l[1], 0, 0, 0);
        // O += P V. V fragments direct from g_vt.
        #pragma unroll
        for (int nd = 0; nd < 4; nd++) {
            size_t drow = (size_t)(nd * 16 + l15) * HW;
            bf16x8 bv0 = *(const bf16x8*)(vbase + drow + t0 + quad * 8);
            bf16x8 bv1 = *(const bf16x8*)(vbase + drow + t0 + (4 + quad) * 8);
            acc_o[0][nd] = __builtin_amdgcn_mfma_f32_16x16x32_bf16(ap[0][0], bv0, acc_o[0][nd], 0, 0, 0);
            acc_o[0][nd] = __builtin_amdgcn_mfma_f32_16x16x32_bf16(ap[0][1], bv1, acc_o[0][nd], 0, 0, 0);
            acc_o[1][nd] = __builtin_amdgcn_mfma_f32_16x16x32_bf16(ap[1][0], bv0, acc_o[1][nd], 0, 0, 0);
            acc_o[1][nd] = __builtin_amdgcn_mfma_f32_16x16x32_bf16(ap[1][1], bv1, acc_o[1][nd], 0, 0, 0);
        }
        // no barrier: pt4 is wave-private, K/V reads are read-only global
    }
    // Epilogue: l for m=quad*4+r sits in acc_l[g][r] (no shuffles needed).
    #pragma unroll
    for (int g = 0; g < 2; g++) {
        #pragma unroll
        for (int r = 0; r < 4; r++) {
            float invl = 1.f / acc_l[g][r];
            size_t row = (size_t)(b * HW + qrow0 + g * 16 + quad * 4 + r);
            #pragma unroll
            for (int nd = 0; nd < 4; nd++)
                g_attno[row * NC + h * DHEAD + nd * 16 + l15] = f2b(acc_o[g][nd][r] * invl);
        }
    }
}

// ---------------------------------------------------------------------------
// Kernel 4: out-proj GEMM + residual, m97 structure. (R16 version)
// ---------------------------------------------------------------------------
__global__ __launch_bounds__(256) void gemm_out(
    const float* __restrict__ xres, float* __restrict__ out) {
    const int K = NC;
    int tid = threadIdx.x, lane = tid & 63, wid = tid >> 6;
    int quad = lane >> 4, l15 = lane & 15;
    int row0 = blockIdx.x * 128;   // o
    int col0 = blockIdx.y * 128;   // bs
    __shared__ alignas(16) short sa[128 * 32];
    __shared__ alignas(16) short sbuf[128 * 32];
    int srow = wid * 32 + (lane >> 2);
    int scol = (lane & 3) * 8;
    const short* ga = g_wout  + (size_t)(row0 + srow) * K + scol;
    const short* gb = g_attno + (size_t)(col0 + srow) * K + scol;
    short* la = sa   + wid * 1024;
    short* lb = sbuf + wid * 1024;
    int mw = (wid >> 1) * 64, nw = (wid & 1) * 64;
    f32x4 acc[4][4] = {};
    for (int k = 0; k < K; k += 32) {
        GLL16(ga + k, la);
        GLL16(ga + (size_t)16 * K + k, la + 512);
        GLL16(gb + k, lb);
        GLL16(gb + (size_t)16 * K + k, lb + 512);
        __syncthreads();
        bf16x8 af[4], bfv[4];
        #pragma unroll
        for (int m = 0; m < 4; m++) af[m]  = *(const bf16x8*)&sa[(mw + m * 16 + l15) * 32 + quad * 8];
        #pragma unroll
        for (int n = 0; n < 4; n++) bfv[n] = *(const bf16x8*)&sbuf[(nw + n * 16 + l15) * 32 + quad * 8];
        #pragma unroll
        for (int m = 0; m < 4; m++)
            #pragma unroll
            for (int n = 0; n < 4; n++)
                acc[m][n] = __builtin_amdgcn_mfma_f32_16x16x32_bf16(af[m], bfv[n], acc[m][n], 0, 0, 0);
        __syncthreads();
    }
    #pragma unroll
    for (int m = 0; m < 4; m++)
        #pragma unroll
        for (int n = 0; n < 4; n++)
            #pragma unroll
            for (int r = 0; r < 4; r++) {
                int o  = row0 + mw + m * 16 + quad * 4 + r;
                int bs = col0 + nw + n * 16 + l15;
                size_t addr = (size_t)(bs >> 10) * ((size_t)NC * HW) + (size_t)o * HW + (bs & 1023);
                out[addr] = acc[m][n][r] + xres[addr];
            }
}

// ---------------------------------------------------------------------------
extern "C" void kernel_launch(void* const* d_in, const int* in_sizes, int n_in,
                              void* d_out, int out_size, void* d_ws, size_t ws_size,
                              hipStream_t stream) {
    const float* x     = (const float*)d_in[0];
    const float* gamma = (const float*)d_in[1];
    const float* beta  = (const float*)d_in[2];
    const float* wqkv  = (const float*)d_in[3];
    const float* wout  = (const float*)d_in[4];
    float* out = (float*)d_out;

    prep_kernel<<<dim3(320), dim3(256), 0, stream>>>(x, gamma, beta, wqkv, wout);
    gemm_qkv<<<dim3(64, 12), dim3(256), 0, stream>>>();
    transpose_v<<<dim3(1024), dim3(256), 0, stream>>>();
    attn_kernel<<<dim3(512), dim3(256), 0, stream>>>();
    gemm_out<<<dim3(4, 64), dim3(256), 0, stream>>>(x, out);
}

// Round 9
// 155.966 us; speedup vs baseline: 1.1779x; 1.1779x over previous
//
#include <hip/hip_runtime.h>

// Problem: B=8, C=512, H*W=1024 spatial, 8 heads x d=64, GROUPS=32.
// Pipeline: prep(GN+weights) -> QKV GEMM -> V-transpose -> attn -> out-proj.
// Round 21: REVERT R20 (direct-global attn: 65us, occupancy stayed 20% --
// grid 512=2 blocks/CU was the binder, not LDS). New attn: 16 q-rows/wave,
// grid 1024 (16 qt x 64 bh), LDS 40KB (kt 2x8 + vt 2x8 + pt4 single 8KB)
// -> 4 blocks/CU = 16 waves/CU (2x TLP of R19). R16 VALU diet kept (2^S,
// cvt_pk, ones-MFMA l). T15 dropped: TLP replaces ILP at 4 waves/SIMD.
// R15-corrected budget: qkv<=11, prep<=5.4, trans<=3.6, out<=7.2 -- attn
// (~23us) is the only kernel with headroom. Other kernels = R19.

typedef __attribute__((ext_vector_type(8))) short bf16x8;   // 8 bf16 in 4 VGPRs
typedef __attribute__((ext_vector_type(4))) short bf16x4;   // 4 bf16 (8B)
typedef __attribute__((ext_vector_type(4))) float f32x4;

#define NB 8
#define NC 512
#define HW 1024
#define NHEAD 8
#define DHEAD 64
#define GROUPS 32
#define CPG 16          // channels per group
#define QKV_N 1536

// global -> LDS direct copy, 16B per lane; lds base must be wave-uniform.
#define GLL16(gaddr, ldsaddr)                                                  \
    __builtin_amdgcn_global_load_lds(                                          \
        (const __attribute__((address_space(1))) unsigned*)(gaddr),            \
        (__attribute__((address_space(3))) unsigned*)(ldsaddr), 16, 0, 0)

// Scratch in device globals.
__device__ alignas(64) short g_xn[(size_t)8192 * 512];      // GN out, pixel-major [bs][c]
__device__ alignas(64) short g_qkv[(size_t)8192 * 1536];    // QKV GEMM out [bs][3C]
__device__ alignas(64) short g_vt[(size_t)64 * 64 * 1024];  // V^T [b*8+h][d][s]
__device__ alignas(64) short g_attno[(size_t)8192 * 512];   // attention out [bs][c]
__device__ alignas(64) short g_wqkv[(size_t)1536 * 512];    // w_qkv as bf16 [o][c]
__device__ alignas(64) short g_wout[(size_t)512 * 512];     // w_out as bf16 [o][c]

__device__ __forceinline__ float b2f(short h) {
    union { unsigned u; float f; } v;
    v.u = ((unsigned)(unsigned short)h) << 16;
    return v.f;
}
__device__ __forceinline__ short f2b(float f) {
    union { float f; unsigned u; } v;
    v.f = f;
    unsigned r = v.u + 0x7fff + ((v.u >> 16) & 1);   // RNE
    return (short)(r >> 16);
}

// ---------------------------------------------------------------------------
// Kernel 1: prep = GroupNorm (blocks 0..255) + weight conversion (256..319).
// ---------------------------------------------------------------------------
__global__ __launch_bounds__(256) void prep_kernel(
    const float* __restrict__ x, const float* __restrict__ gamma,
    const float* __restrict__ beta, const float* __restrict__ wqkv,
    const float* __restrict__ wout) {
    int tid = threadIdx.x;
    if (blockIdx.x >= 256) {                 // ---- weight conversion part
        int wb = blockIdx.x - 256;           // 0..63
        for (int i = wb * 256 + tid; i < 1536 * 512; i += 64 * 256) {
            float v = wqkv[i];
            // Q rows: fold 1/sqrt(d) AND log2(e) so attn P = 2^S (raw v_exp).
            if (i < 512 * 512) v *= 0.18033688011112042f;
            g_wqkv[i] = f2b(v);
        }
        for (int i = wb * 256 + tid; i < 512 * 512; i += 64 * 256)
            g_wout[i] = f2b(wout[i]);
        return;
    }
    // ---- GroupNorm part
    int b = blockIdx.x >> 5, g = blockIdx.x & 31;
    __shared__ alignas(16) short tile[CPG][HW];          // 32 KB
    __shared__ float red[2][4];
    __shared__ float sg[CPG], sb[CPG];
    if (tid < CPG) {
        int cg = g * CPG + tid;
        sg[tid] = gamma[cg];
        sb[tid] = beta[cg];
    }
    const float* xb = x + (size_t)b * NC * HW + (size_t)g * CPG * HW;
    float s1 = 0.f, s2 = 0.f;
    #pragma unroll
    for (int it = 0; it < 8; it++) {
        int idx = tid + it * 256;
        f32x4 v0 = *(const f32x4*)(xb + idx * 8);
        f32x4 v1 = *(const f32x4*)(xb + idx * 8 + 4);
        bf16x8 w;
        #pragma unroll
        for (int j = 0; j < 4; j++) {
            s1 += v0[j] + v1[j]; s2 += v0[j] * v0[j] + v1[j] * v1[j];
            w[j] = f2b(v0[j]); w[j + 4] = f2b(v1[j]);
        }
        *(bf16x8*)(&((short*)tile)[idx * 8]) = w;
    }
    #pragma unroll
    for (int off = 32; off; off >>= 1) { s1 += __shfl_xor(s1, off); s2 += __shfl_xor(s2, off); }
    int wid = tid >> 6;
    if ((tid & 63) == 0) { red[0][wid] = s1; red[1][wid] = s2; }
    __syncthreads();
    float t1 = red[0][0] + red[0][1] + red[0][2] + red[0][3];
    float t2 = red[1][0] + red[1][1] + red[1][2] + red[1][3];
    float mean = t1 * (1.f / 16384.f);
    float var  = t2 * (1.f / 16384.f) - mean * mean;
    float inv  = rsqrtf(var + 1e-5f);
    #pragma unroll
    for (int p = 0; p < 4; p++) {
        int s = tid * 4 + p;
        bf16x8 pk0, pk1;
        #pragma unroll
        for (int cc = 0; cc < 8; cc++) {
            pk0[cc] = f2b((b2f(tile[cc][s])     - mean) * inv * sg[cc]     + sb[cc]);
            pk1[cc] = f2b((b2f(tile[cc + 8][s]) - mean) * inv * sg[cc + 8] + sb[cc + 8]);
        }
        size_t dst = ((size_t)(b * HW + s)) * NC + g * CPG;
        *(bf16x8*)(g_xn + dst)     = pk0;
        *(bf16x8*)(g_xn + dst + 8) = pk1;
    }
}

// ---------------------------------------------------------------------------
// Kernel 2: QKV GEMM. M=8192 N=1536 K=512. BK=64 + XOR swizzle (r18).
// ---------------------------------------------------------------------------
__global__ __launch_bounds__(256) void gemm_qkv() {
    const int K = NC;
    int tid = threadIdx.x, lane = tid & 63, wid = tid >> 6;
    int quad = lane >> 4, l15 = lane & 15;
    int row0 = blockIdx.x * 128;
    int col0 = blockIdx.y * 128;
    __shared__ alignas(16) short sa[128 * 64];   // 16 KB, granule-swizzled
    __shared__ alignas(16) short sbuf[128 * 64]; // 16 KB, granule-swizzled
    int r_lo = lane >> 3;                        // row within 8-row stripe
    int s_log = (lane & 7) ^ r_lo;               // pre-swizzled source granule
    int swz = l15 & 7;                           // fragment-read swizzle
    const short* ga = g_xn   + (size_t)(row0 + wid * 32 + r_lo) * K + s_log * 8;
    const short* gb = g_wqkv + (size_t)(col0 + wid * 32 + r_lo) * K + s_log * 8;
    int mw = (wid >> 1) * 64, nw = (wid & 1) * 64;
    f32x4 acc[4][4] = {};
    for (int k = 0; k < K; k += 64) {
        #pragma unroll
        for (int c = 0; c < 4; c++) {
            GLL16(ga + (size_t)(c * 8) * K + k, &sa[(wid * 32 + c * 8) * 64]);
            GLL16(gb + (size_t)(c * 8) * K + k, &sbuf[(wid * 32 + c * 8) * 64]);
        }
        __syncthreads();
        bf16x8 af0[4], af1[4], bf0[4], bf1[4];
        #pragma unroll
        for (int m = 0; m < 4; m++) {
            int row = mw + m * 16 + l15;
            af0[m] = *(const bf16x8*)&sa[row * 64 + ((quad ^ swz) * 8)];
            af1[m] = *(const bf16x8*)&sa[row * 64 + (((4 + quad) ^ swz) * 8)];
        }
        #pragma unroll
        for (int n = 0; n < 4; n++) {
            int row = nw + n * 16 + l15;
            bf0[n] = *(const bf16x8*)&sbuf[row * 64 + ((quad ^ swz) * 8)];
            bf1[n] = *(const bf16x8*)&sbuf[row * 64 + (((4 + quad) ^ swz) * 8)];
        }
        #pragma unroll
        for (int m = 0; m < 4; m++)
            #pragma unroll
            for (int n = 0; n < 4; n++) {
                acc[m][n] = __builtin_amdgcn_mfma_f32_16x16x32_bf16(af0[m], bf0[n], acc[m][n], 0, 0, 0);
                acc[m][n] = __builtin_amdgcn_mfma_f32_16x16x32_bf16(af1[m], bf1[n], acc[m][n], 0, 0, 0);
            }
        __syncthreads();
    }
    #pragma unroll
    for (int m = 0; m < 4; m++)
        #pragma unroll
        for (int n = 0; n < 4; n++)
            #pragma unroll
            for (int r = 0; r < 4; r++) {
                int row = row0 + mw + m * 16 + quad * 4 + r;
                int col = col0 + nw + n * 16 + l15;
                g_qkv[(size_t)row * QKV_N + col] = f2b(acc[m][n][r]);
            }
}

// ---------------------------------------------------------------------------
// Kernel 2b: V transpose. g_qkv V-part [bs][c] -> g_vt[bh][d][s].
// ---------------------------------------------------------------------------
__global__ __launch_bounds__(256) void transpose_v() {
    int bh = blockIdx.x & 63, st = blockIdx.x >> 6;     // grid 1024
    int b = bh >> 3, h = bh & 7;
    int tid = threadIdx.x;
    __shared__ alignas(16) short tile[64][72];
    int s0 = st * 64;
    #pragma unroll
    for (int cc = 0; cc < 2; cc++) {
        int idx = tid + cc * 256;
        int s = idx >> 3, dc = idx & 7;
        *(bf16x8*)&tile[s][dc * 8] =
            *(const bf16x8*)(g_qkv + ((size_t)(b * HW + s0 + s)) * QKV_N + 1024 + h * DHEAD + dc * 8);
    }
    __syncthreads();
    #pragma unroll
    for (int cc = 0; cc < 2; cc++) {
        int idx = tid + cc * 256;
        int d = idx & 63, sc = idx >> 6;                // sc wave-uniform
        bf16x8 o;
        #pragma unroll
        for (int j = 0; j < 8; j++) o[j] = tile[sc * 8 + j][d];
        *(bf16x8*)(g_vt + ((size_t)(bh * 64 + d)) * HW + s0 + sc * 8) = o;
    }
}

// ---------------------------------------------------------------------------
// Kernel 3: flash attention, 16 q-rows/wave, high-occupancy (r21).
// Grid 1024: bh = blk&63 (XCD L2 sharing), qt = blk>>6 (0..15).
// 4 waves x 16 q-rows = 64 q-rows/block. LDS 40KB (kt 2x8 + vt 2x8 + pt4 8)
// -> 4 blocks/CU = 16 waves/CU. R16 VALU diet: P=2^S, cvt_pk, ones-MFMA l.
// ---------------------------------------------------------------------------
__global__ __launch_bounds__(256) void attn_kernel() {
    int bh = blockIdx.x & 63, qt = blockIdx.x >> 6;
    int b = bh >> 3, h = bh & 7;
    int tid = threadIdx.x, lane = tid & 63, wid = tid >> 6;
    int quad = lane >> 4, l15 = lane & 15;
    __shared__ alignas(16) short kt[2][64 * 64];    // 8 KB each, swizzled
    __shared__ alignas(16) short vt[2][64 * 64];    // 8 KB each, swizzled
    __shared__ alignas(16) short pt4[4][16][16][4]; // per-wave P, 2 KB each
    int qrow0 = qt * 64 + wid * 16;

    const short* qb = g_qkv + ((size_t)(b * HW + qrow0 + l15)) * QKV_N + h * DHEAD + quad * 8;
    bf16x8 aq0 = *(const bf16x8*)qb;
    bf16x8 aq1 = *(const bf16x8*)(qb + 32);
    f32x4 acc_o[4] = {};
    f32x4 acc_l = {};                                // l via ones-MFMA
    bf16x8 vone;
    #pragma unroll
    for (int j = 0; j < 8; j++) vone[j] = (short)0x3f80;   // bf16 1.0

    int r_lo = lane >> 3;
    int s_log = (lane & 7) ^ r_lo;
    int swz = l15 & 7;                               // fragment-read swizzle

    auto stage = [&](int it, int bufi) {
        int t0 = it * 64;
        #pragma unroll
        for (int c = 0; c < 2; c++) {
            int r = wid * 16 + c * 8 + r_lo;
            GLL16(g_qkv + ((size_t)(b * HW + t0 + r)) * QKV_N + 512 + h * DHEAD + s_log * 8,
                  &kt[bufi][(wid * 16 + c * 8) * 64]);
            GLL16(g_vt + ((size_t)(bh * 64 + r)) * HW + t0 + s_log * 8,
                  &vt[bufi][(wid * 16 + c * 8) * 64]);
        }
    };

    stage(0, 0);
    __syncthreads();
    for (int it = 0; it < 16; it++) {
        int cur = it & 1;
        if (it < 15) stage(it + 1, cur ^ 1);        // prefetch into alt buffer
        // S^T(64t x 16m) = K Q^T, then P = 2^S, cvt_pk-packed into pt4.
        #pragma unroll
        for (int sub = 0; sub < 4; sub++) {
            int row = sub * 16 + l15;
            bf16x8 k0 = *(const bf16x8*)&kt[cur][row * 64 + ((quad ^ swz) * 8)];
            bf16x8 k1 = *(const bf16x8*)&kt[cur][row * 64 + (((4 + quad) ^ swz) * 8)];
            f32x4 z = {};
            z = __builtin_amdgcn_mfma_f32_16x16x32_bf16(k0, aq0, z, 0, 0, 0);
            z = __builtin_amdgcn_mfma_f32_16x16x32_bf16(k1, aq1, z, 0, 0, 0);
            float e0, e1, e2, e3;
            asm("v_exp_f32 %0, %1" : "=v"(e0) : "v"(z[0]));
            asm("v_exp_f32 %0, %1" : "=v"(e1) : "v"(z[1]));
            asm("v_exp_f32 %0, %1" : "=v"(e2) : "v"(z[2]));
            asm("v_exp_f32 %0, %1" : "=v"(e3) : "v"(z[3]));
            union { unsigned w[2]; bf16x4 s; } pk;
            asm("v_cvt_pk_bf16_f32 %0, %1, %2" : "=v"(pk.w[0]) : "v"(e0), "v"(e1));
            asm("v_cvt_pk_bf16_f32 %0, %1, %2" : "=v"(pk.w[1]) : "v"(e2), "v"(e3));
            *(bf16x4*)&pt4[wid][sub * 4 + quad][l15][0] = pk.s;
        }
        asm volatile("" ::: "memory");               // order pt4 writes vs reads
        // A-frags of P: lane m=l15, t=half*32+quad*8+j -> two b64 per frag.
        bf16x8 ap0, ap1;
        {
            union { bf16x4 hh[2]; bf16x8 v; } cc;
            cc.hh[0] = *(const bf16x4*)&pt4[wid][quad * 2][l15][0];
            cc.hh[1] = *(const bf16x4*)&pt4[wid][quad * 2 + 1][l15][0];
            ap0 = cc.v;
            cc.hh[0] = *(const bf16x4*)&pt4[wid][8 + quad * 2][l15][0];
            cc.hh[1] = *(const bf16x4*)&pt4[wid][8 + quad * 2 + 1][l15][0];
            ap1 = cc.v;
        }
        // l += P * 1 (ones-B MFMA; D[m][*] replicated across l15 lanes).
        acc_l = __builtin_amdgcn_mfma_f32_16x16x32_bf16(ap0, vone, acc_l, 0, 0, 0);
        acc_l = __builtin_amdgcn_mfma_f32_16x16x32_bf16(ap1, vone, acc_l, 0, 0, 0);
        // O += P V.
        #pragma unroll
        for (int nd = 0; nd < 4; nd++) {
            int row = nd * 16 + l15;
            bf16x8 bv0 = *(const bf16x8*)&vt[cur][row * 64 + ((quad ^ swz) * 8)];
            bf16x8 bv1 = *(const bf16x8*)&vt[cur][row * 64 + (((4 + quad) ^ swz) * 8)];
            acc_o[nd] = __builtin_amdgcn_mfma_f32_16x16x32_bf16(ap0, bv0, acc_o[nd], 0, 0, 0);
            acc_o[nd] = __builtin_amdgcn_mfma_f32_16x16x32_bf16(ap1, bv1, acc_o[nd], 0, 0, 0);
        }
        __syncthreads();   // drains prefetch GLLs + all tile reads
    }
    // Epilogue: l for m=quad*4+r sits in acc_l[r] (no shuffles needed).
    #pragma unroll
    for (int r = 0; r < 4; r++) {
        float invl = 1.f / acc_l[r];
        size_t row = (size_t)(b * HW + qrow0 + quad * 4 + r);
        #pragma unroll
        for (int nd = 0; nd < 4; nd++)
            g_attno[row * NC + h * DHEAD + nd * 16 + l15] = f2b(acc_o[nd][r] * invl);
    }
}

// ---------------------------------------------------------------------------
// Kernel 4: out-proj GEMM + residual, m97 structure. (R16 version)
// ---------------------------------------------------------------------------
__global__ __launch_bounds__(256) void gemm_out(
    const float* __restrict__ xres, float* __restrict__ out) {
    const int K = NC;
    int tid = threadIdx.x, lane = tid & 63, wid = tid >> 6;
    int quad = lane >> 4, l15 = lane & 15;
    int row0 = blockIdx.x * 128;   // o
    int col0 = blockIdx.y * 128;   // bs
    __shared__ alignas(16) short sa[128 * 32];
    __shared__ alignas(16) short sbuf[128 * 32];
    int srow = wid * 32 + (lane >> 2);
    int scol = (lane & 3) * 8;
    const short* ga = g_wout  + (size_t)(row0 + srow) * K + scol;
    const short* gb = g_attno + (size_t)(col0 + srow) * K + scol;
    short* la = sa   + wid * 1024;
    short* lb = sbuf + wid * 1024;
    int mw = (wid >> 1) * 64, nw = (wid & 1) * 64;
    f32x4 acc[4][4] = {};
    for (int k = 0; k < K; k += 32) {
        GLL16(ga + k, la);
        GLL16(ga + (size_t)16 * K + k, la + 512);
        GLL16(gb + k, lb);
        GLL16(gb + (size_t)16 * K + k, lb + 512);
        __syncthreads();
        bf16x8 af[4], bfv[4];
        #pragma unroll
        for (int m = 0; m < 4; m++) af[m]  = *(const bf16x8*)&sa[(mw + m * 16 + l15) * 32 + quad * 8];
        #pragma unroll
        for (int n = 0; n < 4; n++) bfv[n] = *(const bf16x8*)&sbuf[(nw + n * 16 + l15) * 32 + quad * 8];
        #pragma unroll
        for (int m = 0; m < 4; m++)
            #pragma unroll
            for (int n = 0; n < 4; n++)
                acc[m][n] = __builtin_amdgcn_mfma_f32_16x16x32_bf16(af[m], bfv[n], acc[m][n], 0, 0, 0);
        __syncthreads();
    }
    #pragma unroll
    for (int m = 0; m < 4; m++)
        #pragma unroll
        for (int n = 0; n < 4; n++)
            #pragma unroll
            for (int r = 0; r < 4; r++) {
                int o  = row0 + mw + m * 16 + quad * 4 + r;
                int bs = col0 + nw + n * 16 + l15;
                size_t addr = (size_t)(bs >> 10) * ((size_t)NC * HW) + (size_t)o * HW + (bs & 1023);
                out[addr] = acc[m][n][r] + xres[addr];
            }
}

// ---------------------------------------------------------------------------
extern "C" void kernel_launch(void* const* d_in, const int* in_sizes, int n_in,
                              void* d_out, int out_size, void* d_ws, size_t ws_size,
                              hipStream_t stream) {
    const float* x     = (const float*)d_in[0];
    const float* gamma = (const float*)d_in[1];
    const float* beta  = (const float*)d_in[2];
    const float* wqkv  = (const float*)d_in[3];
    const float* wout  = (const float*)d_in[4];
    float* out = (float*)d_out;

    prep_kernel<<<dim3(320), dim3(256), 0, stream>>>(x, gamma, beta, wqkv, wout);
    gemm_qkv<<<dim3(64, 12), dim3(256), 0, stream>>>();
    transpose_v<<<dim3(1024), dim3(256), 0, stream>>>();
    attn_kernel<<<dim3(1024), dim3(256), 0, stream>>>();
    gemm_out<<<dim3(4, 64), dim3(256), 0, stream>>>(x, out);
}

// Round 10
// 151.916 us; speedup vs baseline: 1.2093x; 1.0267x over previous
//
#include <hip/hip_runtime.h>

// Problem: B=8, C=512, H*W=1024 spatial, 8 heads x d=64, GROUPS=32.
// Pipeline: prep(GN+weights) -> QKV GEMM -> V-transpose -> attn -> out-proj.
// Round 22: attn = R19 T15 double-pipeline + SINGLE-SLOT pt4. The 2nd pt4
// slot was unneeded: ap(it) is pulled to regs BEFORE qk_exppack overwrites
// pt4 (wave-private, same-wave LDS in-order -> WAR safe). LDS 64->48KB ->
// 3 blocks/CU (12 waves/CU, was 8) WITH T15 ILP. __launch_bounds__(256,3)
// caps VGPR at 170 (body ~140). Evidence: T15@2blk=152.4 beat noT15@4blk=156
// and noT15@3blk=159 -- this round gets ILP+TLP together. Others = R21.

typedef __attribute__((ext_vector_type(8))) short bf16x8;   // 8 bf16 in 4 VGPRs
typedef __attribute__((ext_vector_type(4))) short bf16x4;   // 4 bf16 (8B)
typedef __attribute__((ext_vector_type(4))) float f32x4;

#define NB 8
#define NC 512
#define HW 1024
#define NHEAD 8
#define DHEAD 64
#define GROUPS 32
#define CPG 16          // channels per group
#define QKV_N 1536

// global -> LDS direct copy, 16B per lane; lds base must be wave-uniform.
#define GLL16(gaddr, ldsaddr)                                                  \
    __builtin_amdgcn_global_load_lds(                                          \
        (const __attribute__((address_space(1))) unsigned*)(gaddr),            \
        (__attribute__((address_space(3))) unsigned*)(ldsaddr), 16, 0, 0)

// Scratch in device globals.
__device__ alignas(64) short g_xn[(size_t)8192 * 512];      // GN out, pixel-major [bs][c]
__device__ alignas(64) short g_qkv[(size_t)8192 * 1536];    // QKV GEMM out [bs][3C]
__device__ alignas(64) short g_vt[(size_t)64 * 64 * 1024];  // V^T [b*8+h][d][s]
__device__ alignas(64) short g_attno[(size_t)8192 * 512];   // attention out [bs][c]
__device__ alignas(64) short g_wqkv[(size_t)1536 * 512];    // w_qkv as bf16 [o][c]
__device__ alignas(64) short g_wout[(size_t)512 * 512];     // w_out as bf16 [o][c]

__device__ __forceinline__ float b2f(short h) {
    union { unsigned u; float f; } v;
    v.u = ((unsigned)(unsigned short)h) << 16;
    return v.f;
}
__device__ __forceinline__ short f2b(float f) {
    union { float f; unsigned u; } v;
    v.f = f;
    unsigned r = v.u + 0x7fff + ((v.u >> 16) & 1);   // RNE
    return (short)(r >> 16);
}

// ---------------------------------------------------------------------------
// Kernel 1: prep = GroupNorm (blocks 0..255) + weight conversion (256..319).
// ---------------------------------------------------------------------------
__global__ __launch_bounds__(256) void prep_kernel(
    const float* __restrict__ x, const float* __restrict__ gamma,
    const float* __restrict__ beta, const float* __restrict__ wqkv,
    const float* __restrict__ wout) {
    int tid = threadIdx.x;
    if (blockIdx.x >= 256) {                 // ---- weight conversion part
        int wb = blockIdx.x - 256;           // 0..63
        for (int i = wb * 256 + tid; i < 1536 * 512; i += 64 * 256) {
            float v = wqkv[i];
            // Q rows: fold 1/sqrt(d) AND log2(e) so attn P = 2^S (raw v_exp).
            if (i < 512 * 512) v *= 0.18033688011112042f;
            g_wqkv[i] = f2b(v);
        }
        for (int i = wb * 256 + tid; i < 512 * 512; i += 64 * 256)
            g_wout[i] = f2b(wout[i]);
        return;
    }
    // ---- GroupNorm part
    int b = blockIdx.x >> 5, g = blockIdx.x & 31;
    __shared__ alignas(16) short tile[CPG][HW];          // 32 KB
    __shared__ float red[2][4];
    __shared__ float sg[CPG], sb[CPG];
    if (tid < CPG) {
        int cg = g * CPG + tid;
        sg[tid] = gamma[cg];
        sb[tid] = beta[cg];
    }
    const float* xb = x + (size_t)b * NC * HW + (size_t)g * CPG * HW;
    float s1 = 0.f, s2 = 0.f;
    #pragma unroll
    for (int it = 0; it < 8; it++) {
        int idx = tid + it * 256;
        f32x4 v0 = *(const f32x4*)(xb + idx * 8);
        f32x4 v1 = *(const f32x4*)(xb + idx * 8 + 4);
        bf16x8 w;
        #pragma unroll
        for (int j = 0; j < 4; j++) {
            s1 += v0[j] + v1[j]; s2 += v0[j] * v0[j] + v1[j] * v1[j];
            w[j] = f2b(v0[j]); w[j + 4] = f2b(v1[j]);
        }
        *(bf16x8*)(&((short*)tile)[idx * 8]) = w;
    }
    #pragma unroll
    for (int off = 32; off; off >>= 1) { s1 += __shfl_xor(s1, off); s2 += __shfl_xor(s2, off); }
    int wid = tid >> 6;
    if ((tid & 63) == 0) { red[0][wid] = s1; red[1][wid] = s2; }
    __syncthreads();
    float t1 = red[0][0] + red[0][1] + red[0][2] + red[0][3];
    float t2 = red[1][0] + red[1][1] + red[1][2] + red[1][3];
    float mean = t1 * (1.f / 16384.f);
    float var  = t2 * (1.f / 16384.f) - mean * mean;
    float inv  = rsqrtf(var + 1e-5f);
    #pragma unroll
    for (int p = 0; p < 4; p++) {
        int s = tid * 4 + p;
        bf16x8 pk0, pk1;
        #pragma unroll
        for (int cc = 0; cc < 8; cc++) {
            pk0[cc] = f2b((b2f(tile[cc][s])     - mean) * inv * sg[cc]     + sb[cc]);
            pk1[cc] = f2b((b2f(tile[cc + 8][s]) - mean) * inv * sg[cc + 8] + sb[cc + 8]);
        }
        size_t dst = ((size_t)(b * HW + s)) * NC + g * CPG;
        *(bf16x8*)(g_xn + dst)     = pk0;
        *(bf16x8*)(g_xn + dst + 8) = pk1;
    }
}

// ---------------------------------------------------------------------------
// Kernel 2: QKV GEMM. M=8192 N=1536 K=512. BK=64 + XOR swizzle (r18).
// ---------------------------------------------------------------------------
__global__ __launch_bounds__(256) void gemm_qkv() {
    const int K = NC;
    int tid = threadIdx.x, lane = tid & 63, wid = tid >> 6;
    int quad = lane >> 4, l15 = lane & 15;
    int row0 = blockIdx.x * 128;
    int col0 = blockIdx.y * 128;
    __shared__ alignas(16) short sa[128 * 64];   // 16 KB, granule-swizzled
    __shared__ alignas(16) short sbuf[128 * 64]; // 16 KB, granule-swizzled
    int r_lo = lane >> 3;                        // row within 8-row stripe
    int s_log = (lane & 7) ^ r_lo;               // pre-swizzled source granule
    int swz = l15 & 7;                           // fragment-read swizzle
    const short* ga = g_xn   + (size_t)(row0 + wid * 32 + r_lo) * K + s_log * 8;
    const short* gb = g_wqkv + (size_t)(col0 + wid * 32 + r_lo) * K + s_log * 8;
    int mw = (wid >> 1) * 64, nw = (wid & 1) * 64;
    f32x4 acc[4][4] = {};
    for (int k = 0; k < K; k += 64) {
        #pragma unroll
        for (int c = 0; c < 4; c++) {
            GLL16(ga + (size_t)(c * 8) * K + k, &sa[(wid * 32 + c * 8) * 64]);
            GLL16(gb + (size_t)(c * 8) * K + k, &sbuf[(wid * 32 + c * 8) * 64]);
        }
        __syncthreads();
        bf16x8 af0[4], af1[4], bf0[4], bf1[4];
        #pragma unroll
        for (int m = 0; m < 4; m++) {
            int row = mw + m * 16 + l15;
            af0[m] = *(const bf16x8*)&sa[row * 64 + ((quad ^ swz) * 8)];
            af1[m] = *(const bf16x8*)&sa[row * 64 + (((4 + quad) ^ swz) * 8)];
        }
        #pragma unroll
        for (int n = 0; n < 4; n++) {
            int row = nw + n * 16 + l15;
            bf0[n] = *(const bf16x8*)&sbuf[row * 64 + ((quad ^ swz) * 8)];
            bf1[n] = *(const bf16x8*)&sbuf[row * 64 + (((4 + quad) ^ swz) * 8)];
        }
        #pragma unroll
        for (int m = 0; m < 4; m++)
            #pragma unroll
            for (int n = 0; n < 4; n++) {
                acc[m][n] = __builtin_amdgcn_mfma_f32_16x16x32_bf16(af0[m], bf0[n], acc[m][n], 0, 0, 0);
                acc[m][n] = __builtin_amdgcn_mfma_f32_16x16x32_bf16(af1[m], bf1[n], acc[m][n], 0, 0, 0);
            }
        __syncthreads();
    }
    #pragma unroll
    for (int m = 0; m < 4; m++)
        #pragma unroll
        for (int n = 0; n < 4; n++)
            #pragma unroll
            for (int r = 0; r < 4; r++) {
                int row = row0 + mw + m * 16 + quad * 4 + r;
                int col = col0 + nw + n * 16 + l15;
                g_qkv[(size_t)row * QKV_N + col] = f2b(acc[m][n][r]);
            }
}

// ---------------------------------------------------------------------------
// Kernel 2b: V transpose. g_qkv V-part [bs][c] -> g_vt[bh][d][s].
// ---------------------------------------------------------------------------
__global__ __launch_bounds__(256) void transpose_v() {
    int bh = blockIdx.x & 63, st = blockIdx.x >> 6;     // grid 1024
    int b = bh >> 3, h = bh & 7;
    int tid = threadIdx.x;
    __shared__ alignas(16) short tile[64][72];
    int s0 = st * 64;
    #pragma unroll
    for (int cc = 0; cc < 2; cc++) {
        int idx = tid + cc * 256;
        int s = idx >> 3, dc = idx & 7;
        *(bf16x8*)&tile[s][dc * 8] =
            *(const bf16x8*)(g_qkv + ((size_t)(b * HW + s0 + s)) * QKV_N + 1024 + h * DHEAD + dc * 8);
    }
    __syncthreads();
    #pragma unroll
    for (int cc = 0; cc < 2; cc++) {
        int idx = tid + cc * 256;
        int d = idx & 63, sc = idx >> 6;                // sc wave-uniform
        bf16x8 o;
        #pragma unroll
        for (int j = 0; j < 8; j++) o[j] = tile[sc * 8 + j][d];
        *(bf16x8*)(g_vt + ((size_t)(bh * 64 + d)) * HW + s0 + sc * 8) = o;
    }
}

// ---------------------------------------------------------------------------
// Kernel 3: flash attention, 32 q-rows/wave, T15 + single-slot pt4 (r22).
// Grid 512: bh = blk&63, qt = blk>>6. P = 2^S; cvt_pk pack; l via ones-MFMA.
// Body(it): pull ap(it)/bv(it) to regs -> sync -> stage(it+2, buf cur) ->
// QK(it+1)+exp->pt4 (WAR-safe: same-wave LDS in-order) || l+PV(it).
// LDS: kt16 + vt16 + pt4 16 = 48KB -> 3 blocks/CU with T15 ILP.
// ---------------------------------------------------------------------------
__global__ __launch_bounds__(256, 3) void attn_kernel() {
    int bh = blockIdx.x & 63, qt = blockIdx.x >> 6;
    int b = bh >> 3, h = bh & 7;
    int tid = threadIdx.x, lane = tid & 63, wid = tid >> 6;
    int quad = lane >> 4, l15 = lane & 15;
    __shared__ alignas(16) short kt[2][64 * 64];    // 8 KB each, swizzled
    __shared__ alignas(16) short vt[2][64 * 64];    // 8 KB each, swizzled
    __shared__ alignas(16) short pt4[4][16][32][4]; // per-wave P, single slot
    int qrow0 = qt * 128 + wid * 32;

    const short* qb0 = g_qkv + ((size_t)(b * HW + qrow0 + l15)) * QKV_N + h * DHEAD + quad * 8;
    const short* qb1 = g_qkv + ((size_t)(b * HW + qrow0 + 16 + l15)) * QKV_N + h * DHEAD + quad * 8;
    bf16x8 aq0 = *(const bf16x8*)qb0;
    bf16x8 aq1 = *(const bf16x8*)(qb0 + 32);
    bf16x8 aq2 = *(const bf16x8*)qb1;
    bf16x8 aq3 = *(const bf16x8*)(qb1 + 32);
    f32x4 acc_o[2][4] = {};
    f32x4 acc_l[2] = {};                             // l via ones-MFMA
    bf16x8 vone;
    #pragma unroll
    for (int j = 0; j < 8; j++) vone[j] = (short)0x3f80;   // bf16 1.0

    int r_lo = lane >> 3;
    int s_log = (lane & 7) ^ r_lo;
    int swz = l15 & 7;                               // fragment-read swizzle

    auto stage = [&](int it, int bufi) {
        int t0 = it * 64;
        #pragma unroll
        for (int c = 0; c < 2; c++) {
            int r = wid * 16 + c * 8 + r_lo;
            GLL16(g_qkv + ((size_t)(b * HW + t0 + r)) * QKV_N + 512 + h * DHEAD + s_log * 8,
                  &kt[bufi][(wid * 16 + c * 8) * 64]);
            GLL16(g_vt + ((size_t)(bh * 64 + r)) * HW + t0 + s_log * 8,
                  &vt[bufi][(wid * 16 + c * 8) * 64]);
        }
    };

    // QK^T of tile in kt[buf], P = 2^S packed into pt4 (single slot).
    auto qk_exppack = [&](int buf) {
        #pragma unroll
        for (int sub = 0; sub < 4; sub++) {
            int row = sub * 16 + l15;
            bf16x8 k0 = *(const bf16x8*)&kt[buf][row * 64 + ((quad ^ swz) * 8)];
            bf16x8 k1 = *(const bf16x8*)&kt[buf][row * 64 + (((4 + quad) ^ swz) * 8)];
            f32x4 z0 = {}, z1 = {};
            z0 = __builtin_amdgcn_mfma_f32_16x16x32_bf16(k0, aq0, z0, 0, 0, 0);
            z0 = __builtin_amdgcn_mfma_f32_16x16x32_bf16(k1, aq1, z0, 0, 0, 0);
            z1 = __builtin_amdgcn_mfma_f32_16x16x32_bf16(k0, aq2, z1, 0, 0, 0);
            z1 = __builtin_amdgcn_mfma_f32_16x16x32_bf16(k1, aq3, z1, 0, 0, 0);
            #pragma unroll
            for (int g = 0; g < 2; g++) {
                f32x4 z = g ? z1 : z0;
                float e0, e1, e2, e3;
                asm("v_exp_f32 %0, %1" : "=v"(e0) : "v"(z[0]));
                asm("v_exp_f32 %0, %1" : "=v"(e1) : "v"(z[1]));
                asm("v_exp_f32 %0, %1" : "=v"(e2) : "v"(z[2]));
                asm("v_exp_f32 %0, %1" : "=v"(e3) : "v"(z[3]));
                union { unsigned w[2]; bf16x4 s; } pk;
                asm("v_cvt_pk_bf16_f32 %0, %1, %2" : "=v"(pk.w[0]) : "v"(e0), "v"(e1));
                asm("v_cvt_pk_bf16_f32 %0, %1, %2" : "=v"(pk.w[1]) : "v"(e2), "v"(e3));
                *(bf16x4*)&pt4[wid][sub * 4 + quad][g * 16 + l15][0] = pk.s;
            }
        }
        asm volatile("" ::: "memory");               // order pt4 writes vs later reads
    };

    // Prologue: two tiles in flight, P(0) packed.
    stage(0, 0);
    __syncthreads();
    stage(1, 1);
    qk_exppack(0);

    for (int it = 0; it < 15; it++) {
        int cur = it & 1, alt = cur ^ 1;
        // ---- pull P(it) and V(it) into regs BEFORE overwrite/barrier ----
        bf16x8 ap[2][2];
        #pragma unroll
        for (int g = 0; g < 2; g++) {
            union { bf16x4 hh[2]; bf16x8 v; } cc;
            cc.hh[0] = *(const bf16x4*)&pt4[wid][quad * 2][g * 16 + l15][0];
            cc.hh[1] = *(const bf16x4*)&pt4[wid][quad * 2 + 1][g * 16 + l15][0];
            ap[g][0] = cc.v;
            cc.hh[0] = *(const bf16x4*)&pt4[wid][8 + quad * 2][g * 16 + l15][0];
            cc.hh[1] = *(const bf16x4*)&pt4[wid][8 + quad * 2 + 1][g * 16 + l15][0];
            ap[g][1] = cc.v;
        }
        asm volatile("" ::: "memory");               // reads before qk_exppack writes
        bf16x8 bv[4][2];
        #pragma unroll
        for (int nd = 0; nd < 4; nd++) {
            int row = nd * 16 + l15;
            bv[nd][0] = *(const bf16x8*)&vt[cur][row * 64 + ((quad ^ swz) * 8)];
            bv[nd][1] = *(const bf16x8*)&vt[cur][row * 64 + (((4 + quad) ^ swz) * 8)];
        }
        __syncthreads();              // stage(it+1) landed; all lgkm drained
        if (it < 14) stage(it + 2, cur);   // reuse buf cur (contents now in regs)
        // ---- QK+exp of it+1 (VALU) interleaves with l+PV of it (MFMA) ----
        qk_exppack(alt);
        acc_l[0] = __builtin_amdgcn_mfma_f32_16x16x32_bf16(ap[0][0], vone, acc_l[0], 0, 0, 0);
        acc_l[0] = __builtin_amdgcn_mfma_f32_16x16x32_bf16(ap[0][1], vone, acc_l[0], 0, 0, 0);
        acc_l[1] = __builtin_amdgcn_mfma_f32_16x16x32_bf16(ap[1][0], vone, acc_l[1], 0, 0, 0);
        acc_l[1] = __builtin_amdgcn_mfma_f32_16x16x32_bf16(ap[1][1], vone, acc_l[1], 0, 0, 0);
        #pragma unroll
        for (int nd = 0; nd < 4; nd++) {
            acc_o[0][nd] = __builtin_amdgcn_mfma_f32_16x16x32_bf16(ap[0][0], bv[nd][0], acc_o[0][nd], 0, 0, 0);
            acc_o[0][nd] = __builtin_amdgcn_mfma_f32_16x16x32_bf16(ap[0][1], bv[nd][1], acc_o[0][nd], 0, 0, 0);
            acc_o[1][nd] = __builtin_amdgcn_mfma_f32_16x16x32_bf16(ap[1][0], bv[nd][0], acc_o[1][nd], 0, 0, 0);
            acc_o[1][nd] = __builtin_amdgcn_mfma_f32_16x16x32_bf16(ap[1][1], bv[nd][1], acc_o[1][nd], 0, 0, 0);
        }
    }
    // ---- epilogue tile 15: P(15) packed by body it=14; V in vt[1] ----
    {
        bf16x8 ap[2][2];
        #pragma unroll
        for (int g = 0; g < 2; g++) {
            union { bf16x4 hh[2]; bf16x8 v; } cc;
            cc.hh[0] = *(const bf16x4*)&pt4[wid][quad * 2][g * 16 + l15][0];
            cc.hh[1] = *(const bf16x4*)&pt4[wid][quad * 2 + 1][g * 16 + l15][0];
            ap[g][0] = cc.v;
            cc.hh[0] = *(const bf16x4*)&pt4[wid][8 + quad * 2][g * 16 + l15][0];
            cc.hh[1] = *(const bf16x4*)&pt4[wid][8 + quad * 2 + 1][g * 16 + l15][0];
            ap[g][1] = cc.v;
        }
        acc_l[0] = __builtin_amdgcn_mfma_f32_16x16x32_bf16(ap[0][0], vone, acc_l[0], 0, 0, 0);
        acc_l[0] = __builtin_amdgcn_mfma_f32_16x16x32_bf16(ap[0][1], vone, acc_l[0], 0, 0, 0);
        acc_l[1] = __builtin_amdgcn_mfma_f32_16x16x32_bf16(ap[1][0], vone, acc_l[1], 0, 0, 0);
        acc_l[1] = __builtin_amdgcn_mfma_f32_16x16x32_bf16(ap[1][1], vone, acc_l[1], 0, 0, 0);
        #pragma unroll
        for (int nd = 0; nd < 4; nd++) {
            int row = nd * 16 + l15;
            bf16x8 bv0 = *(const bf16x8*)&vt[1][row * 64 + ((quad ^ swz) * 8)];
            bf16x8 bv1 = *(const bf16x8*)&vt[1][row * 64 + (((4 + quad) ^ swz) * 8)];
            acc_o[0][nd] = __builtin_amdgcn_mfma_f32_16x16x32_bf16(ap[0][0], bv0, acc_o[0][nd], 0, 0, 0);
            acc_o[0][nd] = __builtin_amdgcn_mfma_f32_16x16x32_bf16(ap[0][1], bv1, acc_o[0][nd], 0, 0, 0);
            acc_o[1][nd] = __builtin_amdgcn_mfma_f32_16x16x32_bf16(ap[1][0], bv0, acc_o[1][nd], 0, 0, 0);
            acc_o[1][nd] = __builtin_amdgcn_mfma_f32_16x16x32_bf16(ap[1][1], bv1, acc_o[1][nd], 0, 0, 0);
        }
    }
    // Epilogue: l for m=quad*4+r sits in acc_l[g][r] (no shuffles needed).
    #pragma unroll
    for (int g = 0; g < 2; g++) {
        #pragma unroll
        for (int r = 0; r < 4; r++) {
            float invl = 1.f / acc_l[g][r];
            size_t row = (size_t)(b * HW + qrow0 + g * 16 + quad * 4 + r);
            #pragma unroll
            for (int nd = 0; nd < 4; nd++)
                g_attno[row * NC + h * DHEAD + nd * 16 + l15] = f2b(acc_o[g][nd][r] * invl);
        }
    }
}

// ---------------------------------------------------------------------------
// Kernel 4: out-proj GEMM + residual, m97 structure. (R16 version)
// ---------------------------------------------------------------------------
__global__ __launch_bounds__(256) void gemm_out(
    const float* __restrict__ xres, float* __restrict__ out) {
    const int K = NC;
    int tid = threadIdx.x, lane = tid & 63, wid = tid >> 6;
    int quad = lane >> 4, l15 = lane & 15;
    int row0 = blockIdx.x * 128;   // o
    int col0 = blockIdx.y * 128;   // bs
    __shared__ alignas(16) short sa[128 * 32];
    __shared__ alignas(16) short sbuf[128 * 32];
    int srow = wid * 32 + (lane >> 2);
    int scol = (lane & 3) * 8;
    const short* ga = g_wout  + (size_t)(row0 + srow) * K + scol;
    const short* gb = g_attno + (size_t)(col0 + srow) * K + scol;
    short* la = sa   + wid * 1024;
    short* lb = sbuf + wid * 1024;
    int mw = (wid >> 1) * 64, nw = (wid & 1) * 64;
    f32x4 acc[4][4] = {};
    for (int k = 0; k < K; k += 32) {
        GLL16(ga + k, la);
        GLL16(ga + (size_t)16 * K + k, la + 512);
        GLL16(gb + k, lb);
        GLL16(gb + (size_t)16 * K + k, lb + 512);
        __syncthreads();
        bf16x8 af[4], bfv[4];
        #pragma unroll
        for (int m = 0; m < 4; m++) af[m]  = *(const bf16x8*)&sa[(mw + m * 16 + l15) * 32 + quad * 8];
        #pragma unroll
        for (int n = 0; n < 4; n++) bfv[n] = *(const bf16x8*)&sbuf[(nw + n * 16 + l15) * 32 + quad * 8];
        #pragma unroll
        for (int m = 0; m < 4; m++)
            #pragma unroll
            for (int n = 0; n < 4; n++)
                acc[m][n] = __builtin_amdgcn_mfma_f32_16x16x32_bf16(af[m], bfv[n], acc[m][n], 0, 0, 0);
        __syncthreads();
    }
    #pragma unroll
    for (int m = 0; m < 4; m++)
        #pragma unroll
        for (int n = 0; n < 4; n++)
            #pragma unroll
            for (int r = 0; r < 4; r++) {
                int o  = row0 + mw + m * 16 + quad * 4 + r;
                int bs = col0 + nw + n * 16 + l15;
                size_t addr = (size_t)(bs >> 10) * ((size_t)NC * HW) + (size_t)o * HW + (bs & 1023);
                out[addr] = acc[m][n][r] + xres[addr];
            }
}

// ---------------------------------------------------------------------------
extern "C" void kernel_launch(void* const* d_in, const int* in_sizes, int n_in,
                              void* d_out, int out_size, void* d_ws, size_t ws_size,
                              hipStream_t stream) {
    const float* x     = (const float*)d_in[0];
    const float* gamma = (const float*)d_in[1];
    const float* beta  = (const float*)d_in[2];
    const float* wqkv  = (const float*)d_in[3];
    const float* wout  = (const float*)d_in[4];
    float* out = (float*)d_out;

    prep_kernel<<<dim3(320), dim3(256), 0, stream>>>(x, gamma, beta, wqkv, wout);
    gemm_qkv<<<dim3(64, 12), dim3(256), 0, stream>>>();
    transpose_v<<<dim3(1024), dim3(256), 0, stream>>>();
    attn_kernel<<<dim3(512), dim3(256), 0, stream>>>();
    gemm_out<<<dim3(4, 64), dim3(256), 0, stream>>>(x, out);
}